// Round 12
// baseline (108.696 us; speedup 1.0000x reference)
//
#include <hip/hip_runtime.h>
#include <hip/hip_fp16.h>

#define BB 16
#define HH 512
#define ROWLEN 1536   // W*C
#define KK 51
#define RR 25

// chunk-level XOR swizzle (involution): spreads strided chunk patterns over
// all 8 bank groups; bijective (only low 3 bits change).
__device__ __forceinline__ int sq(int q) { return q ^ ((q >> 3) & 7); }

// ---------------- K0: reduce 2D kernel to 1D weights (g[i] = row sum) -------
__global__ void k_weights(const float* __restrict__ k2d, float* __restrict__ g) {
    int i = threadIdx.x;
    if (i < KK) {
        float s = 0.f;
        for (int j = 0; j < KK; ++j) s += k2d[i * KK + j];
        g[i] = s;
    }
}

// ---------------- H-pass: 51-tap conv along w, per channel ------------------
// 4 rows/block, 512 threads = 4 rows x 128 lanes. Thread owns 4 pixels x 3
// channels = 12 consecutive flat outputs. Plane element e = w+28, chunk-
// swizzled: addr = plane*576 + 4*sq(e>>2) + (e&3). Compute guard structure
// (proven R5/R8): innermost constant-bound acc loop, compile-time affine
// guard -> 612 FMAs, fully static. Output: fp16, 3 coalesced uint2/thread.
// U8=false additionally writes an fp16 copy of img (imgh) for P2/P4.
#define PSTR 576     // floats per plane = 144 chunks (multiple of 8)
template<bool U8>
__global__ __launch_bounds__(512, 4) void k_hconv(const void* __restrict__ srcv,
                                                  __half* __restrict__ dst,
                                                  __half* __restrict__ imgh,
                                                  const float* __restrict__ gsrc) {
    __shared__ __align__(16) float pl[12 * PSTR];
    const int t = threadIdx.x;
    const int row0 = blockIdx.x * 4;             // first of 4 rows (b*512+h)

    float gw[KK];
    #pragma unroll
    for (int i = 0; i < KK; ++i) gw[i] = gsrc[i];   // uniform -> scalar regs

    const int r = t >> 7;             // row 0..3
    const int l = t & 127;            // lane group; pixels w0 = 4l..4l+3
    const size_t rb = (size_t)(row0 + r) * ROWLEN;

    // ---- load 12 consecutive flats, register-transpose into 3 planes ----
    {
        float f[12];
        if (U8) {
            const unsigned char* s8 = (const unsigned char*)srcv + rb + 12 * l;
            unsigned int ww[3];
            ww[0] = *(const unsigned int*)(s8);
            ww[1] = *(const unsigned int*)(s8 + 4);
            ww[2] = *(const unsigned int*)(s8 + 8);
            #pragma unroll
            for (int k = 0; k < 12; ++k)
                f[k] = (float)((ww[k >> 2] >> ((k & 3) * 8)) & 0xffu);
        } else {
            const float* sf = (const float*)srcv + rb + 12 * l;
            *(float4*)&f[0] = *(const float4*)(sf);
            *(float4*)&f[4] = *(const float4*)(sf + 4);
            *(float4*)&f[8] = *(const float4*)(sf + 8);
            // fp16 copy of img for downstream passes
            union { __half h[12]; uint2 u2[3]; } pi;
            #pragma unroll
            for (int k = 0; k < 12; ++k) pi.h[k] = __float2half_rn(f[k]);
            uint2* ip = (uint2*)(imgh + rb + 12 * l);
            ip[0] = pi.u2[0]; ip[1] = pi.u2[1]; ip[2] = pi.u2[2];
        }
        const int q = sq(7 + l);                 // chunk of e = 28+4l
        #pragma unroll
        for (int c = 0; c < 3; ++c) {
            float4 o;
            o.x = f[c]; o.y = f[3 + c]; o.z = f[6 + c]; o.w = f[9 + c];
            *(float4*)&pl[(r * 3 + c) * PSTR + 4 * q] = o;
        }
    }
    __syncthreads();

    // ---- reflect halos (np.pad 'reflect'): 12 planes x 50 elements ----
    #pragma unroll
    for (int it = 0; it < 2; ++it) {
        const int item = t + it * 512;
        if (item < 600) {
            const int p = item / 50, k = item % 50;
            int ed, es;
            if (k < 25) { const int j = k + 1;  ed = 28 - j;  es = 28 + j; }
            else        { const int j = k - 24; ed = 539 + j; es = 539 - j; }
            float* pb = &pl[p * PSTR];
            pb[4 * sq(ed >> 2) + (ed & 3)] = pb[4 * sq(es >> 2) + (es & 3)];
        }
    }
    __syncthreads();

    // ---- compute: acc[c][a] = channel c, pixel w0+a ----
    float acc[3][4];
    #pragma unroll
    for (int c = 0; c < 3; ++c)
        #pragma unroll
        for (int a = 0; a < 4; ++a) acc[c][a] = 0.f;

    #pragma unroll
    for (int c = 0; c < 3; ++c) {
        const float* pb = &pl[(r * 3 + c) * PSTR];
        #pragma unroll
        for (int v = 0; v < 15; ++v) {
            const float4 v4 = *(const float4*)&pb[4 * sq(l + v)];
            #pragma unroll
            for (int mm = 0; mm < 4; ++mm) {
                const float val = (&v4.x)[mm];
                #pragma unroll
                for (int a = 0; a < 4; ++a) {
                    const int jj = 4 * v + mm - a - 3;   // tap, compile-time
                    if (jj >= 0 && jj < KK) acc[c][a] += gw[jj] * val;
                }
            }
        }
    }

    // ---- store: 12 consecutive fp16 flats = 3 coalesced uint2 ----
    union { __half h[12]; uint2 u2[3]; } pk;
    #pragma unroll
    for (int a = 0; a < 4; ++a)
        #pragma unroll
        for (int c = 0; c < 3; ++c) pk.h[3 * a + c] = __float2half_rn(acc[c][a]);
    uint2* dp = (uint2*)(dst + rb + 12 * l);
    dp[0] = pk.u2[0]; dp[1] = pk.u2[1]; dp[2] = pk.u2[2];
}

// ---------------- V-pass: 51-tap conv along h + fused epilogue --------------
// Tile: 64 flat cols x 128 output rows (+50 halo), f32 in LDS (converted from
// fp16 src on load). Row stride 68 dw + 16B pad every 8 rows:
// rowoff(r) = r*68 + (r>>3)*4. This breaks the rg-cohort bank alias (any
// 16B-aligned uniform stride puts all 4 rg groups of a wave on the SAME banks
// -> 4-way conflict on every b128; the group pad lands rg at dword offsets
// {0,4,8,12} mod 32 -> conflict-free). Read offsets stay compile-time:
// off(jj) = jj*68 + (jj>>3)*4, thread base = rg*548 + 4*cg.
// 256 threads = 16 col-groups x 16 row-groups of 8 rows: 32 outputs/thread.
// MODE 0: v-blur tbuf -> blur (regs only); sharp=clip(img+0.5(img-blur)) ->
//         sharp16 (fp16), mask -> mask8. blur is never written to memory.
// MODE 1: v-blur tbuf -> soft mask; read imgh + sharp16; final -> outp (f32).
#define FW 64
#define HC 128
#define VROWS 178    // HC + 2*RR
#define TILEDW (VROWS * 68 + (VROWS / 8) * 4)   // 12192 dw = 48768 B

__device__ __forceinline__ int rowoff(int r) { return r * 68 + (r >> 3) * 4; }

template<int MODE>
__global__ __launch_bounds__(256) void k_vconv(const __half* __restrict__ src,
                                               const __half* __restrict__ imgh,
                                               __half* __restrict__ sharp16,
                                               float* __restrict__ outp,
                                               unsigned char* __restrict__ mask8,
                                               const float* __restrict__ gsrc) {
    __shared__ __align__(16) float tile[TILEDW];
    const int t  = threadIdx.x;
    const int cg = t & 15;               // col group: cols 4*cg..4*cg+3
    const int rg = t >> 4;               // row group: rows rg*8..rg*8+7
    const int bid = blockIdx.x;
    const int wcB = bid % 24;
    const int hB  = (bid / 24) & 3;
    const int b   = bid / 96;
    const int wc0 = wcB * 64;
    const int h0  = hB * HC;

    float gw[KK];
    #pragma unroll
    for (int i = 0; i < KK; ++i) gw[i] = gsrc[i];

    const size_t imgbase = (size_t)b * HH * ROWLEN;

    // ---- load tile (178 rows x 16 chunks of 4 fp16) with reflect on h ----
    #pragma unroll
    for (int i = 0; i < 12; ++i) {
        const int m = t + 256 * i;
        if (m < VROWS * 16) {
            const int r = m >> 4, cc = m & 15;
            int hs = h0 - RR + r;
            hs = hs < 0 ? -hs : hs;
            hs = hs > 511 ? 1022 - hs : hs;
            union { uint2 u2; __half2 h2[2]; } ld;
            ld.u2 = *(const uint2*)&src[imgbase + (size_t)hs * ROWLEN + wc0 + 4 * cc];
            const float2 fa = __half22float2(ld.h2[0]);
            const float2 fb = __half22float2(ld.h2[1]);
            float4 o; o.x = fa.x; o.y = fa.y; o.z = fb.x; o.w = fb.y;
            *(float4*)&tile[rowoff(r) + 4 * cc] = o;
        }
    }
    __syncthreads();

    float acc[8][4];
    #pragma unroll
    for (int a = 0; a < 8; ++a)
        #pragma unroll
        for (int m = 0; m < 4; ++m) acc[a][m] = 0.f;

    const float* base = &tile[rg * 548 + 4 * cg];   // rowoff(rg*8) + 4*cg
    #pragma unroll
    for (int jj = 0; jj < 58; ++jj) {
        const float4 v4 = *(const float4*)(base + jj * 68 + (jj >> 3) * 4);
        #pragma unroll
        for (int a = 0; a < 8; ++a) {
            const int tap = jj - a;
            if (tap >= 0 && tap < KK) {
                acc[a][0] += gw[tap] * v4.x;
                acc[a][1] += gw[tap] * v4.y;
                acc[a][2] += gw[tap] * v4.z;
                acc[a][3] += gw[tap] * v4.w;
            }
        }
    }

    // ---- fused epilogue ----
    #pragma unroll
    for (int a = 0; a < 8; ++a) {
        const int hh = h0 + rg * 8 + a;
        const size_t idx = imgbase + (size_t)hh * ROWLEN + wc0 + 4 * cg;
        union { uint2 u2; __half2 h2[2]; } xl;
        xl.u2 = *(const uint2*)&imgh[idx];
        const float2 x0 = __half22float2(xl.h2[0]);
        const float2 x1 = __half22float2(xl.h2[1]);
        const float xv[4] = {x0.x, x0.y, x1.x, x1.y};
        if (MODE == 0) {
            float sh[4];
            unsigned int mw = 0;
            #pragma unroll
            for (int m = 0; m < 4; ++m) {
                const float x = xv[m];
                const float res = x - acc[a][m];
                sh[m] = fminf(fmaxf(x + 0.5f * res, 0.f), 1.f);
                if (fabsf(res) * 255.0f > 10.0f) mw |= (1u << (8 * m));
            }
            *(__half2*)&sharp16[idx]     = __floats2half2_rn(sh[0], sh[1]);
            *(__half2*)&sharp16[idx + 2] = __floats2half2_rn(sh[2], sh[3]);
            *(unsigned int*)&mask8[idx] = mw;
        } else {
            union { uint2 u2; __half2 h2[2]; } sl;
            sl.u2 = *(const uint2*)&sharp16[idx];
            const float2 f0 = __half22float2(sl.h2[0]);
            const float2 f1 = __half22float2(sl.h2[1]);
            const float shv[4] = {f0.x, f0.y, f1.x, f1.y};
            float4 o; float* op = &o.x;
            #pragma unroll
            for (int m = 0; m < 4; ++m) {
                const float x = xv[m];
                op[m] = x + acc[a][m] * (shv[m] - x);
            }
            *(float4*)&outp[idx] = o;
        }
    }
}

// ---------------------------------------------------------------------------
extern "C" void kernel_launch(void* const* d_in, const int* in_sizes, int n_in,
                              void* d_out, int out_size, void* d_ws, size_t ws_size,
                              hipStream_t stream) {
    (void)in_sizes; (void)n_in; (void)out_size; (void)ws_size;
    const float* img = (const float*)d_in[0];
    const float* k2d = (const float*)d_in[1];
    float* out = (float*)d_out;

    const size_t NPX = (size_t)BB * HH * ROWLEN;   // 12.58M flats
    char* ws = (char*)d_ws;
    float* g = (float*)ws;                          // 51 floats (256B slot)
    __half* tbuf = (__half*)(ws + 256);             // 25.2 MB
    unsigned char* mask8 = (unsigned char*)(ws + 256 + NPX * 2);      // 12.6 MB
    __half* sharp16 = (__half*)(ws + 256 + NPX * 2 + NPX);            // 25.2 MB
    __half* imgh    = (__half*)(ws + 256 + NPX * 2 + NPX + NPX * 2);  // 25.2 MB

    const int nhblk = BB * HH / 4;        // 2048
    const int nvblk = BB * 4 * 24;        // 1536

    k_weights<<<1, 64, 0, stream>>>(k2d, g);
    // P1: H-blur img -> tbuf (fp16); also emit imgh (fp16 copy of img)
    k_hconv<false><<<nhblk, 512, 0, stream>>>((const void*)img, tbuf, imgh, g);
    // P2: V-blur tbuf -> blur (regs); sharp16 + mask8 out (reads imgh)
    k_vconv<0><<<nvblk, 256, 0, stream>>>(tbuf, imgh, sharp16, out, mask8, g);
    // P3: H-blur mask8 -> tbuf (fp16)
    k_hconv<true><<<nhblk, 512, 0, stream>>>((const void*)mask8, tbuf, imgh, g);
    // P4: V-blur tbuf -> soft mask; blend imgh/sharp16 -> d_out (f32)
    k_vconv<1><<<nvblk, 256, 0, stream>>>(tbuf, imgh, sharp16, out, mask8, g);
}

// Round 13
// 106.637 us; speedup vs baseline: 1.0193x; 1.0193x over previous
//
#include <hip/hip_runtime.h>
#include <hip/hip_fp16.h>

#define BB 16
#define HH 512
#define ROWLEN 1536   // W*C
#define KK 51
#define RR 25

// chunk-level XOR swizzle (involution): spreads strided chunk patterns over
// all 8 bank groups; bijective (only low 3 bits change).
__device__ __forceinline__ int sq(int q) { return q ^ ((q >> 3) & 7); }

// ---------------- K0: reduce 2D kernel to 1D weights (g[i] = row sum) -------
__global__ void k_weights(const float* __restrict__ k2d, float* __restrict__ g,
                          __half2* __restrict__ g2) {
    int i = threadIdx.x;
    if (i < KK) {
        float s = 0.f;
        for (int j = 0; j < KK; ++j) s += k2d[i * KK + j];
        g[i] = s;
        g2[i] = __float2half2_rn(s);
    }
}

// ---------------- H-pass: 51-tap conv along w, per channel (f32) ------------
// 4 rows/block, 512 threads = 4 rows x 128 lanes. Thread owns 4 pixels x 3
// channels = 12 consecutive flat outputs. Plane element e = w+28, chunk-
// swizzled: addr = plane*576 + 4*sq(e>>2) + (e&3). Proven guard structure
// (R5/R8): innermost constant-bound acc loop, compile-time affine guard.
// Output fp16 (3 uint2/thread). U8=false also emits imgh (fp16 img copy).
#define PSTR 576     // floats per plane = 144 chunks (multiple of 8)
template<bool U8>
__global__ __launch_bounds__(512, 4) void k_hconv(const void* __restrict__ srcv,
                                                  __half* __restrict__ dst,
                                                  __half* __restrict__ imgh,
                                                  const float* __restrict__ gsrc) {
    __shared__ __align__(16) float pl[12 * PSTR];
    const int t = threadIdx.x;
    const int row0 = blockIdx.x * 4;             // first of 4 rows (b*512+h)

    float gw[KK];
    #pragma unroll
    for (int i = 0; i < KK; ++i) gw[i] = gsrc[i];   // uniform -> scalar regs

    const int r = t >> 7;             // row 0..3
    const int l = t & 127;            // lane group; pixels w0 = 4l..4l+3
    const size_t rb = (size_t)(row0 + r) * ROWLEN;

    // ---- load 12 consecutive flats, register-transpose into 3 planes ----
    {
        float f[12];
        if (U8) {
            const unsigned char* s8 = (const unsigned char*)srcv + rb + 12 * l;
            unsigned int ww[3];
            ww[0] = *(const unsigned int*)(s8);
            ww[1] = *(const unsigned int*)(s8 + 4);
            ww[2] = *(const unsigned int*)(s8 + 8);
            #pragma unroll
            for (int k = 0; k < 12; ++k)
                f[k] = (float)((ww[k >> 2] >> ((k & 3) * 8)) & 0xffu);
        } else {
            const float* sf = (const float*)srcv + rb + 12 * l;
            *(float4*)&f[0] = *(const float4*)(sf);
            *(float4*)&f[4] = *(const float4*)(sf + 4);
            *(float4*)&f[8] = *(const float4*)(sf + 8);
            union { __half h[12]; uint2 u2[3]; } pi;
            #pragma unroll
            for (int k = 0; k < 12; ++k) pi.h[k] = __float2half_rn(f[k]);
            uint2* ip = (uint2*)(imgh + rb + 12 * l);
            ip[0] = pi.u2[0]; ip[1] = pi.u2[1]; ip[2] = pi.u2[2];
        }
        const int q = sq(7 + l);                 // chunk of e = 28+4l
        #pragma unroll
        for (int c = 0; c < 3; ++c) {
            float4 o;
            o.x = f[c]; o.y = f[3 + c]; o.z = f[6 + c]; o.w = f[9 + c];
            *(float4*)&pl[(r * 3 + c) * PSTR + 4 * q] = o;
        }
    }
    __syncthreads();

    // ---- reflect halos (np.pad 'reflect'): 12 planes x 50 elements ----
    #pragma unroll
    for (int it = 0; it < 2; ++it) {
        const int item = t + it * 512;
        if (item < 600) {
            const int p = item / 50, k = item % 50;
            int ed, es;
            if (k < 25) { const int j = k + 1;  ed = 28 - j;  es = 28 + j; }
            else        { const int j = k - 24; ed = 539 + j; es = 539 - j; }
            float* pb = &pl[p * PSTR];
            pb[4 * sq(ed >> 2) + (ed & 3)] = pb[4 * sq(es >> 2) + (es & 3)];
        }
    }
    __syncthreads();

    // ---- compute: acc[c][a] = channel c, pixel w0+a ----
    float acc[3][4];
    #pragma unroll
    for (int c = 0; c < 3; ++c)
        #pragma unroll
        for (int a = 0; a < 4; ++a) acc[c][a] = 0.f;

    #pragma unroll
    for (int c = 0; c < 3; ++c) {
        const float* pb = &pl[(r * 3 + c) * PSTR];
        #pragma unroll
        for (int v = 0; v < 15; ++v) {
            const float4 v4 = *(const float4*)&pb[4 * sq(l + v)];
            #pragma unroll
            for (int mm = 0; mm < 4; ++mm) {
                const float val = (&v4.x)[mm];
                #pragma unroll
                for (int a = 0; a < 4; ++a) {
                    const int jj = 4 * v + mm - a - 3;   // tap, compile-time
                    if (jj >= 0 && jj < KK) acc[c][a] += gw[jj] * val;
                }
            }
        }
    }

    // ---- store: 12 consecutive fp16 flats = 3 coalesced uint2 ----
    union { __half h[12]; uint2 u2[3]; } pk;
    #pragma unroll
    for (int a = 0; a < 4; ++a)
        #pragma unroll
        for (int c = 0; c < 3; ++c) pk.h[3 * a + c] = __float2half_rn(acc[c][a]);
    uint2* dp = (uint2*)(dst + rb + 12 * l);
    dp[0] = pk.u2[0]; dp[1] = pk.u2[1]; dp[2] = pk.u2[2];
}

// ---------------- V-pass: 51-tap conv along h, packed fp16 ------------------
// Tile: 64 cols x 128 out rows (+50 halo), fp16 in LDS, row stride 72 halfs
// (144 B: 16B pad keeps b128 alignment and rotates banks by 4 dw/row).
// 256 threads = 8 col-groups (8 cols = 4 half2, one b128/row) x 32 row-groups
// (4 rows). 816 v_pk_fma_f16/thread, guard compile-time (proven structure).
// Accumulate fp16 (err ~2e-3 << 0.02 threshold); epilogues in f32.
// MODE 0: blur(regs) -> sharp16 (fp16) + mask8. MODE 1: soft-mask -> blend
// imgh/sharp16 -> outp (f32).
#define HC 128
#define VROWS 178    // HC + 2*RR
#define HSTR 72      // halfs per row

template<int MODE>
__global__ __launch_bounds__(256) void k_vconv(const __half* __restrict__ src,
                                               const __half* __restrict__ imgh,
                                               __half* __restrict__ sharp16,
                                               float* __restrict__ outp,
                                               unsigned char* __restrict__ mask8,
                                               const __half2* __restrict__ g2src) {
    __shared__ __align__(16) __half tile[VROWS * HSTR];
    const int t  = threadIdx.x;
    const int cg = t & 7;                // col group: cols 8*cg..8*cg+7
    const int rg = t >> 3;               // row group: rows rg*4..rg*4+3
    const int bid = blockIdx.x;
    const int wcB = bid % 24;
    const int hB  = (bid / 24) & 3;
    const int b   = bid / 96;
    const int wc0 = wcB * 64;
    const int h0  = hB * HC;

    __half2 gw2[KK];
    #pragma unroll
    for (int i = 0; i < KK; ++i) gw2[i] = g2src[i];   // uniform -> scalar regs

    const size_t imgbase = (size_t)b * HH * ROWLEN;

    // ---- load tile (178 rows x 8 chunks of 8 halfs) with reflect on h ----
    #pragma unroll
    for (int i = 0; i < 6; ++i) {
        const int m = t + 256 * i;
        if (m < VROWS * 8) {
            const int r = m >> 3, cc = m & 7;
            int hs = h0 - RR + r;
            hs = hs < 0 ? -hs : hs;
            hs = hs > 511 ? 1022 - hs : hs;
            *(uint4*)&tile[r * HSTR + 8 * cc] =
                *(const uint4*)&src[imgbase + (size_t)hs * ROWLEN + wc0 + 8 * cc];
        }
    }
    __syncthreads();

    __half2 acc[4][4];
    const __half2 z2 = __float2half2_rn(0.f);
    #pragma unroll
    for (int a = 0; a < 4; ++a)
        #pragma unroll
        for (int p = 0; p < 4; ++p) acc[a][p] = z2;

    const __half* base = &tile[(rg * 4) * HSTR + 8 * cg];
    #pragma unroll
    for (int jj = 0; jj < 54; ++jj) {
        const uint4 raw = *(const uint4*)(base + jj * HSTR);
        union { uint4 u; __half2 h2[4]; } v; v.u = raw;
        #pragma unroll
        for (int a = 0; a < 4; ++a) {
            const int tap = jj - a;                  // compile-time guard
            if (tap >= 0 && tap < KK) {
                acc[a][0] = __hfma2(gw2[tap], v.h2[0], acc[a][0]);
                acc[a][1] = __hfma2(gw2[tap], v.h2[1], acc[a][1]);
                acc[a][2] = __hfma2(gw2[tap], v.h2[2], acc[a][2]);
                acc[a][3] = __hfma2(gw2[tap], v.h2[3], acc[a][3]);
            }
        }
    }

    // ---- fused epilogue (f32 math, 8 cols per row) ----
    #pragma unroll
    for (int a = 0; a < 4; ++a) {
        const int hh = h0 + rg * 4 + a;
        const size_t idx = imgbase + (size_t)hh * ROWLEN + wc0 + 8 * cg;
        union { uint4 u; __half2 h2[4]; } xl;
        xl.u = *(const uint4*)&imgh[idx];
        float xv[8], bv[8];
        #pragma unroll
        for (int p = 0; p < 4; ++p) {
            const float2 xf = __half22float2(xl.h2[p]);
            const float2 bf = __half22float2(acc[a][p]);
            xv[2*p] = xf.x; xv[2*p+1] = xf.y;
            bv[2*p] = bf.x; bv[2*p+1] = bf.y;
        }
        if (MODE == 0) {
            union { __half h[8]; uint4 u; } sh;
            unsigned int mwlo = 0, mwhi = 0;
            #pragma unroll
            for (int m = 0; m < 8; ++m) {
                const float x = xv[m];
                const float res = x - bv[m];
                sh.h[m] = __float2half_rn(fminf(fmaxf(x + 0.5f * res, 0.f), 1.f));
                const unsigned int bit = (fabsf(res) * 255.0f > 10.0f) ? 1u : 0u;
                if (m < 4) mwlo |= bit << (8 * m); else mwhi |= bit << (8 * (m - 4));
            }
            *(uint4*)&sharp16[idx] = sh.u;
            uint2 mo; mo.x = mwlo; mo.y = mwhi;
            *(uint2*)&mask8[idx] = mo;
        } else {
            union { uint4 u; __half2 h2[4]; } sl;
            sl.u = *(const uint4*)&sharp16[idx];
            float4 o0, o1;
            float* op = &o0.x;   // o0,o1 adjacent on stack? keep separate
            float ov[8];
            #pragma unroll
            for (int p = 0; p < 4; ++p) {
                const float2 sf = __half22float2(sl.h2[p]);
                const float x0 = xv[2*p],   s0 = sf.x;
                const float x1 = xv[2*p+1], s1 = sf.y;
                ov[2*p]   = x0 + bv[2*p]   * (s0 - x0);
                ov[2*p+1] = x1 + bv[2*p+1] * (s1 - x1);
            }
            o0.x = ov[0]; o0.y = ov[1]; o0.z = ov[2]; o0.w = ov[3];
            o1.x = ov[4]; o1.y = ov[5]; o1.z = ov[6]; o1.w = ov[7];
            (void)op;
            *(float4*)&outp[idx]     = o0;
            *(float4*)&outp[idx + 4] = o1;
        }
    }
}

// ---------------------------------------------------------------------------
extern "C" void kernel_launch(void* const* d_in, const int* in_sizes, int n_in,
                              void* d_out, int out_size, void* d_ws, size_t ws_size,
                              hipStream_t stream) {
    (void)in_sizes; (void)n_in; (void)out_size; (void)ws_size;
    const float* img = (const float*)d_in[0];
    const float* k2d = (const float*)d_in[1];
    float* out = (float*)d_out;

    const size_t NPX = (size_t)BB * HH * ROWLEN;   // 12.58M flats
    char* ws = (char*)d_ws;
    float* g = (float*)ws;                          // 51 f32 (256B slot)
    __half2* g2 = (__half2*)(ws + 256);             // 51 half2 (256B slot)
    __half* tbuf = (__half*)(ws + 512);             // 25.2 MB
    unsigned char* mask8 = (unsigned char*)(ws + 512 + NPX * 2);      // 12.6 MB
    __half* sharp16 = (__half*)(ws + 512 + NPX * 2 + NPX);            // 25.2 MB
    __half* imgh    = (__half*)(ws + 512 + NPX * 2 + NPX + NPX * 2);  // 25.2 MB

    const int nhblk = BB * HH / 4;        // 2048
    const int nvblk = BB * 4 * 24;        // 1536

    k_weights<<<1, 64, 0, stream>>>(k2d, g, g2);
    // P1: H-blur img -> tbuf (fp16); also emit imgh (fp16 copy of img)
    k_hconv<false><<<nhblk, 512, 0, stream>>>((const void*)img, tbuf, imgh, g);
    // P2: V-blur tbuf -> blur (regs); sharp16 + mask8 out (reads imgh)
    k_vconv<0><<<nvblk, 256, 0, stream>>>(tbuf, imgh, sharp16, out, mask8, g2);
    // P3: H-blur mask8 -> tbuf (fp16)
    k_hconv<true><<<nhblk, 512, 0, stream>>>((const void*)mask8, tbuf, imgh, g);
    // P4: V-blur tbuf -> soft mask; blend imgh/sharp16 -> d_out (f32)
    k_vconv<1><<<nvblk, 256, 0, stream>>>(tbuf, imgh, sharp16, out, mask8, g2);
}

// Round 14
// 95.912 us; speedup vs baseline: 1.1333x; 1.1118x over previous
//
#include <hip/hip_runtime.h>
#include <hip/hip_fp16.h>

#define BB 16
#define HH 512
#define ROWLEN 1536   // W*C
#define KK 51
#define RR 25

// chunk-level XOR swizzle (involution): spreads strided chunk patterns over
// all 8 bank groups; bijective (only low 3 bits change).
__device__ __forceinline__ int sq(int q) { return q ^ ((q >> 3) & 7); }

// ---------------- K0: reduce 2D kernel to 1D weights (g[i] = row sum) -------
__global__ void k_weights(const float* __restrict__ k2d, float* __restrict__ g,
                          __half2* __restrict__ g2) {
    int i = threadIdx.x;
    if (i < KK) {
        float s = 0.f;
        for (int j = 0; j < KK; ++j) s += k2d[i * KK + j];
        g[i] = s;
        g2[i] = __float2half2_rn(s);
    }
}

// ---------------- H-pass: 51-tap conv along w, row-pair packed fp16 ---------
// 4 rows/block, 256 threads = 2 row-pairs x 128 lanes. half2 lanes carry the
// TWO ROWS of a pair (independent convs, same taps -> no unaligned pair
// extraction). Plane = (rowpair, channel): 576 half2 elements, e = w+28,
// chunk-swizzled addr = plane*576 + 4*sq(e>>2) + (e&3) (half2 units: 4B each,
// bank math identical to proven f32 R8 skeleton). Thread owns 4 pixels x 3 ch
// x 2 rows = 24 outputs: 612 hfma2, guard compile-time. Store: 3 uint2 per
// row, coalesced. U8=false also emits imgh (fp16 copy of img, both rows).
#define PSTR 576     // half2 per plane = 144 chunks (multiple of 8)
template<bool U8>
__global__ __launch_bounds__(256, 4) void k_hconv(const void* __restrict__ srcv,
                                                  __half* __restrict__ dst,
                                                  __half* __restrict__ imgh,
                                                  const __half2* __restrict__ g2src) {
    __shared__ __align__(16) __half2 pl[6 * PSTR];
    const int t = threadIdx.x;
    const int row0 = blockIdx.x * 4;             // first of 4 rows (b*512+h)

    __half2 gw2[KK];
    #pragma unroll
    for (int i = 0; i < KK; ++i) gw2[i] = g2src[i];   // uniform

    const int rp = t >> 7;            // row pair 0..1
    const int l  = t & 127;           // lane group; pixels w0 = 4l..4l+3
    const size_t rb0 = (size_t)(row0 + 2 * rp) * ROWLEN;
    const size_t rb1 = rb0 + ROWLEN;

    // ---- load 12 flats of both rows, pack half2 (lo=row0, hi=row1) ----
    {
        float f0[12], f1[12];
        if (U8) {
            const unsigned char* sa = (const unsigned char*)srcv + rb0 + 12 * l;
            const unsigned char* sb = (const unsigned char*)srcv + rb1 + 12 * l;
            unsigned int wa[3], wb[3];
            wa[0] = *(const unsigned int*)(sa);
            wa[1] = *(const unsigned int*)(sa + 4);
            wa[2] = *(const unsigned int*)(sa + 8);
            wb[0] = *(const unsigned int*)(sb);
            wb[1] = *(const unsigned int*)(sb + 4);
            wb[2] = *(const unsigned int*)(sb + 8);
            #pragma unroll
            for (int k = 0; k < 12; ++k) {
                f0[k] = (float)((wa[k >> 2] >> ((k & 3) * 8)) & 0xffu);
                f1[k] = (float)((wb[k >> 2] >> ((k & 3) * 8)) & 0xffu);
            }
        } else {
            const float* sfa = (const float*)srcv + rb0 + 12 * l;
            const float* sfb = (const float*)srcv + rb1 + 12 * l;
            *(float4*)&f0[0] = *(const float4*)(sfa);
            *(float4*)&f0[4] = *(const float4*)(sfa + 4);
            *(float4*)&f0[8] = *(const float4*)(sfa + 8);
            *(float4*)&f1[0] = *(const float4*)(sfb);
            *(float4*)&f1[4] = *(const float4*)(sfb + 4);
            *(float4*)&f1[8] = *(const float4*)(sfb + 8);
            union { __half h[12]; uint2 u2[3]; } pa, pb2;
            #pragma unroll
            for (int k = 0; k < 12; ++k) {
                pa.h[k]  = __float2half_rn(f0[k]);
                pb2.h[k] = __float2half_rn(f1[k]);
            }
            uint2* ipa = (uint2*)(imgh + rb0 + 12 * l);
            uint2* ipb = (uint2*)(imgh + rb1 + 12 * l);
            ipa[0] = pa.u2[0];  ipa[1] = pa.u2[1];  ipa[2] = pa.u2[2];
            ipb[0] = pb2.u2[0]; ipb[1] = pb2.u2[1]; ipb[2] = pb2.u2[2];
        }
        const int q = sq(7 + l);                 // chunk of e = 28+4l
        #pragma unroll
        for (int c = 0; c < 3; ++c) {
            union { __half2 h2[4]; uint4 u; } o;
            #pragma unroll
            for (int i = 0; i < 4; ++i)
                o.h2[i] = __halves2half2(__float2half_rn(f0[3 * i + c]),
                                         __float2half_rn(f1[3 * i + c]));
            *(uint4*)&pl[(rp * 3 + c) * PSTR + 4 * q] = o.u;
        }
    }
    __syncthreads();

    // ---- reflect halos (np.pad 'reflect'): 6 planes x 50 elements ----
    #pragma unroll
    for (int it = 0; it < 2; ++it) {
        const int item = t + it * 256;
        if (item < 300) {
            const int p = item / 50, k = item % 50;
            int ed, es;
            if (k < 25) { const int j = k + 1;  ed = 28 - j;  es = 28 + j; }
            else        { const int j = k - 24; ed = 539 + j; es = 539 - j; }
            __half2* pb = &pl[p * PSTR];
            pb[4 * sq(ed >> 2) + (ed & 3)] = pb[4 * sq(es >> 2) + (es & 3)];
        }
    }
    __syncthreads();

    // ---- compute: acc2[c][a] = channel c, pixel w0+a, both rows ----
    __half2 acc2[3][4];
    const __half2 z2 = __float2half2_rn(0.f);
    #pragma unroll
    for (int c = 0; c < 3; ++c)
        #pragma unroll
        for (int a = 0; a < 4; ++a) acc2[c][a] = z2;

    #pragma unroll
    for (int c = 0; c < 3; ++c) {
        const __half2* pb = &pl[(rp * 3 + c) * PSTR];
        #pragma unroll
        for (int v = 0; v < 15; ++v) {
            union { uint4 u; __half2 h2[4]; } v4;
            v4.u = *(const uint4*)&pb[4 * sq(l + v)];
            #pragma unroll
            for (int mm = 0; mm < 4; ++mm) {
                const __half2 val = v4.h2[mm];
                #pragma unroll
                for (int a = 0; a < 4; ++a) {
                    const int jj = 4 * v + mm - a - 3;   // tap, compile-time
                    if (jj >= 0 && jj < KK)
                        acc2[c][a] = __hfma2(gw2[jj], val, acc2[c][a]);
                }
            }
        }
    }

    // ---- store: per row, 12 consecutive fp16 flats = 3 coalesced uint2 ----
    {
        union { __half h[12]; uint2 u2[3]; } pk;
        #pragma unroll
        for (int a = 0; a < 4; ++a)
            #pragma unroll
            for (int c = 0; c < 3; ++c) pk.h[3 * a + c] = __low2half(acc2[c][a]);
        uint2* dp = (uint2*)(dst + rb0 + 12 * l);
        dp[0] = pk.u2[0]; dp[1] = pk.u2[1]; dp[2] = pk.u2[2];
    }
    {
        union { __half h[12]; uint2 u2[3]; } pk;
        #pragma unroll
        for (int a = 0; a < 4; ++a)
            #pragma unroll
            for (int c = 0; c < 3; ++c) pk.h[3 * a + c] = __high2half(acc2[c][a]);
        uint2* dp = (uint2*)(dst + rb1 + 12 * l);
        dp[0] = pk.u2[0]; dp[1] = pk.u2[1]; dp[2] = pk.u2[2];
    }
}

// ---------------- V-pass: 51-tap conv along h, packed fp16 ------------------
// Tile: 64 cols x 128 out rows (+50 halo), fp16 in LDS, row stride 72 halfs.
// 256 threads = 8 col-groups (8 cols = 4 half2, one b128/row) x 32 row-groups
// (4 rows). 816 v_pk_fma_f16/thread, guard compile-time.
// MODE 0: blur(regs) -> sharp16 (fp16) + mask8. MODE 1: soft-mask -> blend
// imgh/sharp16 -> outp (f32).
#define HC 128
#define VROWS 178    // HC + 2*RR
#define HSTR 72      // halfs per row

template<int MODE>
__global__ __launch_bounds__(256) void k_vconv(const __half* __restrict__ src,
                                               const __half* __restrict__ imgh,
                                               __half* __restrict__ sharp16,
                                               float* __restrict__ outp,
                                               unsigned char* __restrict__ mask8,
                                               const __half2* __restrict__ g2src) {
    __shared__ __align__(16) __half tile[VROWS * HSTR];
    const int t  = threadIdx.x;
    const int cg = t & 7;                // col group: cols 8*cg..8*cg+7
    const int rg = t >> 3;               // row group: rows rg*4..rg*4+3
    const int bid = blockIdx.x;
    const int wcB = bid % 24;
    const int hB  = (bid / 24) & 3;
    const int b   = bid / 96;
    const int wc0 = wcB * 64;
    const int h0  = hB * HC;

    __half2 gw2[KK];
    #pragma unroll
    for (int i = 0; i < KK; ++i) gw2[i] = g2src[i];

    const size_t imgbase = (size_t)b * HH * ROWLEN;

    // ---- load tile (178 rows x 8 chunks of 8 halfs) with reflect on h ----
    #pragma unroll
    for (int i = 0; i < 6; ++i) {
        const int m = t + 256 * i;
        if (m < VROWS * 8) {
            const int r = m >> 3, cc = m & 7;
            int hs = h0 - RR + r;
            hs = hs < 0 ? -hs : hs;
            hs = hs > 511 ? 1022 - hs : hs;
            *(uint4*)&tile[r * HSTR + 8 * cc] =
                *(const uint4*)&src[imgbase + (size_t)hs * ROWLEN + wc0 + 8 * cc];
        }
    }
    __syncthreads();

    __half2 acc[4][4];
    const __half2 z2 = __float2half2_rn(0.f);
    #pragma unroll
    for (int a = 0; a < 4; ++a)
        #pragma unroll
        for (int p = 0; p < 4; ++p) acc[a][p] = z2;

    const __half* base = &tile[(rg * 4) * HSTR + 8 * cg];
    #pragma unroll
    for (int jj = 0; jj < 54; ++jj) {
        const uint4 raw = *(const uint4*)(base + jj * HSTR);
        union { uint4 u; __half2 h2[4]; } v; v.u = raw;
        #pragma unroll
        for (int a = 0; a < 4; ++a) {
            const int tap = jj - a;                  // compile-time guard
            if (tap >= 0 && tap < KK) {
                acc[a][0] = __hfma2(gw2[tap], v.h2[0], acc[a][0]);
                acc[a][1] = __hfma2(gw2[tap], v.h2[1], acc[a][1]);
                acc[a][2] = __hfma2(gw2[tap], v.h2[2], acc[a][2]);
                acc[a][3] = __hfma2(gw2[tap], v.h2[3], acc[a][3]);
            }
        }
    }

    // ---- fused epilogue (f32 math, 8 cols per row) ----
    #pragma unroll
    for (int a = 0; a < 4; ++a) {
        const int hh = h0 + rg * 4 + a;
        const size_t idx = imgbase + (size_t)hh * ROWLEN + wc0 + 8 * cg;
        union { uint4 u; __half2 h2[4]; } xl;
        xl.u = *(const uint4*)&imgh[idx];
        float xv[8], bv[8];
        #pragma unroll
        for (int p = 0; p < 4; ++p) {
            const float2 xf = __half22float2(xl.h2[p]);
            const float2 bf = __half22float2(acc[a][p]);
            xv[2*p] = xf.x; xv[2*p+1] = xf.y;
            bv[2*p] = bf.x; bv[2*p+1] = bf.y;
        }
        if (MODE == 0) {
            union { __half h[8]; uint4 u; } sh;
            unsigned int mwlo = 0, mwhi = 0;
            #pragma unroll
            for (int m = 0; m < 8; ++m) {
                const float x = xv[m];
                const float res = x - bv[m];
                sh.h[m] = __float2half_rn(fminf(fmaxf(x + 0.5f * res, 0.f), 1.f));
                const unsigned int bit = (fabsf(res) * 255.0f > 10.0f) ? 1u : 0u;
                if (m < 4) mwlo |= bit << (8 * m); else mwhi |= bit << (8 * (m - 4));
            }
            *(uint4*)&sharp16[idx] = sh.u;
            uint2 mo; mo.x = mwlo; mo.y = mwhi;
            *(uint2*)&mask8[idx] = mo;
        } else {
            union { uint4 u; __half2 h2[4]; } sl;
            sl.u = *(const uint4*)&sharp16[idx];
            float ov[8];
            #pragma unroll
            for (int p = 0; p < 4; ++p) {
                const float2 sf = __half22float2(sl.h2[p]);
                ov[2*p]   = xv[2*p]   + bv[2*p]   * (sf.x - xv[2*p]);
                ov[2*p+1] = xv[2*p+1] + bv[2*p+1] * (sf.y - xv[2*p+1]);
            }
            float4 o0, o1;
            o0.x = ov[0]; o0.y = ov[1]; o0.z = ov[2]; o0.w = ov[3];
            o1.x = ov[4]; o1.y = ov[5]; o1.z = ov[6]; o1.w = ov[7];
            *(float4*)&outp[idx]     = o0;
            *(float4*)&outp[idx + 4] = o1;
        }
    }
}

// ---------------------------------------------------------------------------
extern "C" void kernel_launch(void* const* d_in, const int* in_sizes, int n_in,
                              void* d_out, int out_size, void* d_ws, size_t ws_size,
                              hipStream_t stream) {
    (void)in_sizes; (void)n_in; (void)out_size; (void)ws_size;
    const float* img = (const float*)d_in[0];
    const float* k2d = (const float*)d_in[1];
    float* out = (float*)d_out;

    const size_t NPX = (size_t)BB * HH * ROWLEN;   // 12.58M flats
    char* ws = (char*)d_ws;
    float* g = (float*)ws;                          // 51 f32 (256B slot)
    __half2* g2 = (__half2*)(ws + 256);             // 51 half2 (256B slot)
    __half* tbuf = (__half*)(ws + 512);             // 25.2 MB
    unsigned char* mask8 = (unsigned char*)(ws + 512 + NPX * 2);      // 12.6 MB
    __half* sharp16 = (__half*)(ws + 512 + NPX * 2 + NPX);            // 25.2 MB
    __half* imgh    = (__half*)(ws + 512 + NPX * 2 + NPX + NPX * 2);  // 25.2 MB

    const int nhblk = BB * HH / 4;        // 2048
    const int nvblk = BB * 4 * 24;        // 1536

    k_weights<<<1, 64, 0, stream>>>(k2d, g, g2);
    // P1: H-blur img -> tbuf (fp16); also emit imgh (fp16 copy of img)
    k_hconv<false><<<nhblk, 256, 0, stream>>>((const void*)img, tbuf, imgh, g2);
    // P2: V-blur tbuf -> blur (regs); sharp16 + mask8 out (reads imgh)
    k_vconv<0><<<nvblk, 256, 0, stream>>>(tbuf, imgh, sharp16, out, mask8, g2);
    // P3: H-blur mask8 -> tbuf (fp16)
    k_hconv<true><<<nhblk, 256, 0, stream>>>((const void*)mask8, tbuf, imgh, g2);
    // P4: V-blur tbuf -> soft mask; blend imgh/sharp16 -> d_out (f32)
    k_vconv<1><<<nvblk, 256, 0, stream>>>(tbuf, imgh, sharp16, out, mask8, g2);
}